// Round 8
// baseline (590.107 us; speedup 1.0000x reference)
//
#include <hip/hip_runtime.h>
#include <hip/hip_bf16.h>

#define N_NODES 262144
#define C_CH 64
#define K_NBR 16
#define NCLS 40

typedef unsigned short ushort_t;
typedef __attribute__((ext_vector_type(8))) short short8;
typedef __attribute__((ext_vector_type(4))) float floatx4;

__device__ __forceinline__ float bu2f(ushort_t u) {
    union { unsigned u32; float f; } v; v.u32 = ((unsigned)u) << 16; return v.f;
}
__device__ __forceinline__ ushort_t f2bu(float f) {
    union { float f; unsigned u; } v; v.f = f;
    unsigned r = v.u + 0x7FFFu + ((v.u >> 16) & 1u);
    return (ushort_t)(r >> 16);
}
__device__ __forceinline__ floatx4 bcast4(float g) {
    floatx4 v; v[0] = g; v[1] = g; v[2] = g; v[3] = g; return v;
}
__device__ __forceinline__ int ldi(const int* p, long i)       { return p[i]; }
__device__ __forceinline__ int ldi(const long long* p, long i) { return (int)p[i]; }

// ---------------- Sniffer: flags[1] = 1 if nbr is int64 ----------------------
__global__ void sniff_kernel(const void* __restrict__ nbr, int* __restrict__ flags) {
    int lane = threadIdx.x;                 // 64 threads
    const int* ni = (const int*)nbr;
    bool zodd = (ni[2 * lane + 1] == 0);    // int64 high words all zero
    unsigned long long mz = __ballot(zodd);
    if (lane == 0) flags[1] = (mz == ~0ULL) ? 1 : 0;
}

// ---------------- Kernel A: CPE depthwise conv3 + residual ------------------
// f32 x -> bf16 h table. One thread = 2 channels (float2) x 4 nodes.
__global__ void cpe_kernel(const float* __restrict__ x,
                           const float* __restrict__ cw,
                           const float* __restrict__ cb,
                           ushort_t* __restrict__ h) {
    int t  = blockIdx.x * 256 + threadIdx.x;   // [0, N/4 * 32)
    int ig = t >> 5;                           // node group (4 nodes)
    int cp = t & 31;                           // channel pair
    int i0 = ig << 2;
    int c0 = cp * 2;
    float w00 = cw[c0*3+0], w01 = cw[c0*3+1], w02 = cw[c0*3+2], b0 = cb[c0];
    float w10 = cw[c0*3+3], w11 = cw[c0*3+4], w12 = cw[c0*3+5], b1 = cb[c0+1];
    float2 v[6];
#pragma unroll
    for (int r = 0; r < 6; ++r) {
        int i = i0 - 1 + r;
        if (i >= 0 && i < N_NODES) v[r] = *(const float2*)(x + (size_t)i * C_CH + c0);
        else                       v[r] = make_float2(0.f, 0.f);
    }
    unsigned* ho = (unsigned*)h;
#pragma unroll
    for (int j = 0; j < 4; ++j) {
        float r0 = v[j+1].x + b0;
        r0 = fmaf(v[j].x, w00, r0); r0 = fmaf(v[j+1].x, w01, r0); r0 = fmaf(v[j+2].x, w02, r0);
        float r1 = v[j+1].y + b1;
        r1 = fmaf(v[j].y, w10, r1); r1 = fmaf(v[j+1].y, w11, r1); r1 = fmaf(v[j+2].y, w12, r1);
        unsigned pack = (unsigned)f2bu(r0) | (((unsigned)f2bu(r1)) << 16);
        ho[((size_t)(i0 + j) * C_CH + c0) >> 1] = pack;
    }
}

// ---------------- Kernel B: gather + max-rel + MFMA proj/head + logsoftmax --
// Wave = 16 nodes/iter. feat rows in per-wave LDS (bf16), proj via
// mfma_f32_16x16x32_bf16 with residual folded into W' = W + [I;0], bias as
// acc-init. h2 LDS round-trip (D-layout -> A-layout), head MFMA, softmax in
// D-layout via intra-quad shuffles.
template <typename IT>
__global__ void graph_head_kernel(const int* __restrict__ flags,
                                  const ushort_t* __restrict__ hws,
                                  const IT* __restrict__ nbr,
                                  const float* __restrict__ gw,
                                  const float* __restrict__ gb,
                                  const float* __restrict__ ow,
                                  const float* __restrict__ ob,
                                  float* __restrict__ out) {
    if ((flags[1] != 0) != (sizeof(IT) == 8)) return;

    // per-wave regions; row strides padded for bank spread, 16B-aligned
    __shared__ __align__(16) ushort_t sFeat[4][16 * 136];  // 17408 B: feat[m][0..127]
    __shared__ __align__(16) ushort_t sH2[4][16 * 72];     //  9216 B: h2[m][0..63]

    const int lane   = threadIdx.x & 63;
    const int wave   = threadIdx.x >> 6;
    const int lanelo = lane & 15;
    const int quad   = lane >> 4;

    // ---- preload B-fragments into registers (once per wave) ----
    // B-layout: lane holds B[k = quad*8+j][n = lanelo] for each (k-step, n-tile)
    short8 wfrag[4][4];
#pragma unroll
    for (int s = 0; s < 4; ++s)
#pragma unroll
        for (int nt = 0; nt < 4; ++nt) {
            short8 f;
#pragma unroll
            for (int j = 0; j < 8; ++j) {
                int k = s * 32 + quad * 8 + j;
                int n = nt * 16 + lanelo;
                float w = gw[k * C_CH + n];
                if (k == n) w += 1.0f;          // residual folded in: W' = W + [I;0]
                f[j] = (short)f2bu(w);
            }
            wfrag[s][nt] = f;
        }
    short8 ofrag[2][3];
#pragma unroll
    for (int s = 0; s < 2; ++s)
#pragma unroll
        for (int nt = 0; nt < 3; ++nt) {
            short8 f;
#pragma unroll
            for (int j = 0; j < 8; ++j) {
                int k = s * 32 + quad * 8 + j;
                int n = nt * 16 + lanelo;
                float w = (n < NCLS) ? ow[k * NCLS + n] : 0.f;
                f[j] = (short)f2bu(w);
            }
            ofrag[s][nt] = f;
        }
    float gbf[4];
#pragma unroll
    for (int nt = 0; nt < 4; ++nt) gbf[nt] = gb[nt * 16 + lanelo];
    float obf[3];
#pragma unroll
    for (int nt = 0; nt < 3; ++nt) {
        int n = nt * 16 + lanelo;
        obf[nt] = (n < NCLS) ? ob[n] : 0.f;
    }

    const bool ok2 = (lanelo < 8);   // n-tile 2 covers cols 32..47; valid n<40

    // 4096 groups of 64 nodes; grid 1024 -> exactly 4 uniform iterations
    for (int g = blockIdx.x; g < (N_NODES >> 6); g += gridDim.x) {
        const int nb0 = g * 64 + wave * 16;
        ushort_t* feat = &sFeat[wave][0];
        ushort_t* h2w  = &sH2[wave][0];

        // ---- gather + max-rel, lane = channel ----
#pragma unroll
        for (int q = 0; q < 4; ++q) {
            int idxv = ldi(nbr, (long)nb0 * K_NBR + q * 64 + lane);
#pragma unroll
            for (int tt = 0; tt < 4; ++tt) {
                int t = q * 4 + tt;
                ushort_t hu = hws[(size_t)(nb0 + t) * C_CH + lane];
                float hif = bu2f(hu);
                float mx = -1e30f;
#pragma unroll
                for (int k = 0; k < 16; ++k) {
                    int j = __shfl(idxv, tt * 16 + k, 64);
                    mx = fmaxf(mx, bu2f(hws[((size_t)(unsigned)j << 6) + lane]));
                }
                feat[t * 136 + lane]      = hu;             // h part (k=0..63)
                feat[t * 136 + 64 + lane] = f2bu(mx - hif); // rel part (k=64..127)
            }
        }
        __syncthreads();

        // ---- proj: D[16x64] = feat[16x128] @ W' + gb ----
        floatx4 acc[4];
#pragma unroll
        for (int nt = 0; nt < 4; ++nt) acc[nt] = bcast4(gbf[nt]);
#pragma unroll
        for (int s = 0; s < 4; ++s) {
            // A-frag: A[m=lanelo][k = s*32 + quad*8 + j]
            short8 af = *(const short8*)(feat + lanelo * 136 + s * 32 + quad * 8);
#pragma unroll
            for (int nt = 0; nt < 4; ++nt)
                acc[nt] = __builtin_amdgcn_mfma_f32_16x16x32_bf16(af, wfrag[s][nt], acc[nt], 0, 0, 0);
        }
        // D-layout: row m = quad*4+r, col n = nt*16+lanelo -> write h2 rows (bf16)
#pragma unroll
        for (int nt = 0; nt < 4; ++nt)
#pragma unroll
            for (int r = 0; r < 4; ++r)
                h2w[(quad * 4 + r) * 72 + nt * 16 + lanelo] = f2bu(acc[nt][r]);
        __syncthreads();

        // ---- head: L[16x48] = h2[16x64] @ ow (+ ob) ----
        floatx4 accH[3];
#pragma unroll
        for (int nt = 0; nt < 3; ++nt) accH[nt] = bcast4(obf[nt]);
#pragma unroll
        for (int s = 0; s < 2; ++s) {
            short8 hf = *(const short8*)(h2w + lanelo * 72 + s * 32 + quad * 8);
#pragma unroll
            for (int nt = 0; nt < 3; ++nt)
                accH[nt] = __builtin_amdgcn_mfma_f32_16x16x32_bf16(hf, ofrag[s][nt], accH[nt], 0, 0, 0);
        }

        // ---- log-softmax per row (reduce over 16 lanes within quad) ----
#pragma unroll
        for (int r = 0; r < 4; ++r) {
            int row = nb0 + quad * 4 + r;
            float v0 = accH[0][r], v1 = accH[1][r];
            float v2 = ok2 ? accH[2][r] : -1e30f;
            float m = fmaxf(fmaxf(v0, v1), v2);
#pragma unroll
            for (int off = 1; off < 16; off <<= 1) m = fmaxf(m, __shfl_xor(m, off, 64));
            float s = __expf(v0 - m) + __expf(v1 - m) + (ok2 ? __expf(v2 - m) : 0.f);
#pragma unroll
            for (int off = 1; off < 16; off <<= 1) s += __shfl_xor(s, off, 64);
            float li = m + __logf(s);
            float* orow = out + (size_t)row * NCLS + lanelo;
            orow[0]  = v0 - li;
            orow[16] = v1 - li;
            if (ok2) orow[32] = v2 - li;
        }
        __syncthreads();
    }
}

extern "C" void kernel_launch(void* const* d_in, const int* in_sizes, int n_in,
                              void* d_out, int out_size, void* d_ws, size_t ws_size,
                              hipStream_t stream) {
    const float* x  = (const float*)d_in[0];
    const float* cw = (const float*)d_in[2];
    const float* cb = (const float*)d_in[3];
    const float* gw = (const float*)d_in[4];
    const float* gb = (const float*)d_in[5];
    const float* ow = (const float*)d_in[6];
    const float* ob = (const float*)d_in[7];
    float* out = (float*)d_out;

    int* flags = (int*)d_ws;
    ushort_t* hws = (ushort_t*)((char*)d_ws + 1024);   // N*64 bf16 = 32 MB

    sniff_kernel<<<1, 64, 0, stream>>>(d_in[1], flags);
    // CPE: N/4 node-groups x 32 channel-pairs = 2.1M threads
    cpe_kernel<<<(N_NODES / 4 * 32) / 256, 256, 0, stream>>>(x, cw, cb, hws);
    // Graph+head: 1024 persistent blocks, 4 uniform iterations each
    graph_head_kernel<int><<<1024, 256, 0, stream>>>(
        flags, hws, (const int*)d_in[1], gw, gb, ow, ob, out);
    graph_head_kernel<long long><<<1024, 256, 0, stream>>>(
        flags, hws, (const long long*)d_in[1], gw, gb, ow, ob, out);
}